// Round 1
// baseline (80.910 us; speedup 1.0000x reference)
//
#include <hip/hip_runtime.h>

#define BATCH 4
#define SEQ   512
#define DIM   128

typedef _Float16 half8 __attribute__((ext_vector_type(8)));
typedef _Float16 half4 __attribute__((ext_vector_type(4)));
typedef float    f32x4 __attribute__((ext_vector_type(4)));

static __device__ __forceinline__ half8 cvt_h8(const float4 a, const float4 b) {
    half8 h;
    h[0] = (_Float16)a.x; h[1] = (_Float16)a.y; h[2] = (_Float16)a.z; h[3] = (_Float16)a.w;
    h[4] = (_Float16)b.x; h[5] = (_Float16)b.y; h[6] = (_Float16)b.z; h[7] = (_Float16)b.w;
    return h;
}

// ---------------------------------------------------------------------------
// K1 proj (fused prep): D[token][col] = x @ W^T for q,k,v simultaneously.
// f32 operands are loaded directly and converted to f16 fragments in-reg
// (same rounding as the old separate prep pass -> numerics identical).
// Wave tile 16m(token) x 16n(col); block = 4 waves stacked in m.
// Grid = 32 x 8 = 256 blocks (one block-wavefront).
// Epilogue:
//   qoutT[b][col][tok] = sigmoid(dq + bq)        (f32, transposed -> float4 store)
//   ekk[b][2c+0][tok] (f16) = exp(dk + bk)               (den operand)
//   ekk[b][2c+1][tok] (f16) = exp(dk + bk)*(dv + bv)     (num operand)
// Tail: each block converts its 1/256 slice of pos -> exp(pos) f16 (ep_h).
// ---------------------------------------------------------------------------
__global__ __launch_bounds__(256) void k_proj(
    const float* __restrict__ x,
    const float* __restrict__ Wq, const float* __restrict__ bq,
    const float* __restrict__ Wk, const float* __restrict__ bk,
    const float* __restrict__ Wv, const float* __restrict__ bv,
    const float* __restrict__ pos,
    float* __restrict__ qoutT, _Float16* __restrict__ ekk,
    _Float16* __restrict__ ep_h)
{
    const int tid  = threadIdx.x;
    const int lane = tid & 63;
    const int wave = tid >> 6;
    const int l15  = lane & 15;
    const int quad = lane >> 4;

    const int n0 = (blockIdx.x & 7) * 16;               // col tile
    const int m0 = (blockIdx.x >> 3) * 64 + wave * 16;  // token-row tile

    const float* xa = x  + (m0 + l15) * DIM + quad * 8;
    const float* wq = Wq + (n0 + l15) * DIM + quad * 8;
    const float* wk = Wk + (n0 + l15) * DIM + quad * 8;
    const float* wv = Wv + (n0 + l15) * DIM + quad * 8;

    f32x4 aq = {0.f, 0.f, 0.f, 0.f};
    f32x4 ak = {0.f, 0.f, 0.f, 0.f};
    f32x4 av = {0.f, 0.f, 0.f, 0.f};

#pragma unroll
    for (int ks = 0; ks < 4; ++ks) {            // K = 128, 32 per step
        const half8 a  = cvt_h8(*(const float4*)(xa + ks * 32),
                                *(const float4*)(xa + ks * 32 + 4));
        const half8 b0 = cvt_h8(*(const float4*)(wq + ks * 32),
                                *(const float4*)(wq + ks * 32 + 4));
        const half8 b1 = cvt_h8(*(const float4*)(wk + ks * 32),
                                *(const float4*)(wk + ks * 32 + 4));
        const half8 b2 = cvt_h8(*(const float4*)(wv + ks * 32),
                                *(const float4*)(wv + ks * 32 + 4));
        aq = __builtin_amdgcn_mfma_f32_16x16x32_f16(a, b0, aq, 0, 0, 0);
        ak = __builtin_amdgcn_mfma_f32_16x16x32_f16(a, b1, ak, 0, 0, 0);
        av = __builtin_amdgcn_mfma_f32_16x16x32_f16(a, b2, av, 0, 0, 0);
    }

    const int c   = n0 + l15;
    const float bqv = bq[c];
    const float bkv = bk[c];
    const float bvv = bv[c];

    const int mrow = m0 + quad * 4;   // first of 4 token rows this lane holds
    const int b    = mrow >> 9;       // /512 (all 4 rows same batch)
    const int tok  = mrow & 511;

    half4 eh, evh;
    float4 q4;
#pragma unroll
    for (int r = 0; r < 4; ++r) {
        const float e  = __expf(ak[r] + bkv);
        const float vv = av[r] + bvv;
        eh[r]  = (_Float16)e;
        evh[r] = (_Float16)(e * vv);
        ((float*)&q4)[r] = 1.f / (1.f + __expf(-(aq[r] + bqv)));
    }
    *(half4*)(ekk + ((b * 256) + 2 * c + 0) * SEQ + tok) = eh;
    *(half4*)(ekk + ((b * 256) + 2 * c + 1) * SEQ + tok) = evh;
    *(float4*)(qoutT + ((b * DIM) + c) * SEQ + tok) = q4;   // transposed, coalesced

    // --- fused pos -> exp(pos) f16 conversion (1/256 slice per block) ---
    const int i = (blockIdx.x * 256 + tid) * 4;
    const float4 p = *(const float4*)(pos + i);
    half4 h;
    h[0] = (_Float16)__expf(p.x); h[1] = (_Float16)__expf(p.y);
    h[2] = (_Float16)__expf(p.z); h[3] = (_Float16)__expf(p.w);
    *(half4*)(ep_h + i) = h;
}

// ---------------------------------------------------------------------------
// K2 AFT (MFMA, zero LDS): per b, D[m][t] = sum_j ekk[m][j] * ep[t][j]
//   m in [0,256): even rows = den (ek), odd rows = num (ekv).
// Wave tile 16m x 16t; block = 8 waves (2m x 4t) = 32m x 64t, 512 threads.
// Grid = 256 blocks -> 8 waves/CU = 2 waves/SIMD (2x the old occupancy).
// Epilogue: out[b][t][d] = qT[b][d][t] * num/den.
// ---------------------------------------------------------------------------
__global__ __launch_bounds__(512, 2) void k_aft(
    const _Float16* __restrict__ ekk,
    const _Float16* __restrict__ ep_h,
    const float* __restrict__ qoutT,
    float* __restrict__ out)
{
    const int tid  = threadIdx.x;
    const int lane = tid & 63;
    const int wave = tid >> 6;      // 0..7
    const int l15  = lane & 15;
    const int quad = lane >> 4;
    const int wm   = wave & 1;
    const int wn   = wave >> 1;     // 0..3

    const int b  = blockIdx.x >> 6;                            // 0..3
    const int m0 = (((blockIdx.x >> 3) & 7) * 32) + wm * 16;   // [0,256)
    const int t0 = ((blockIdx.x & 7) * 64) + wn * 16;          // [0,512)

    const _Float16* arow = ekk  + ((b * 256) + m0 + l15) * SEQ + quad * 8;
    const _Float16* brow = ep_h + (t0 + l15) * SEQ + quad * 8;

    f32x4 acc = {0.f, 0.f, 0.f, 0.f};

#pragma unroll
    for (int ks = 0; ks < 16; ++ks) {           // K = 512, 32 per step
        const half8 a  = *(const half8*)(arow + ks * 32);
        const half8 bf = *(const half8*)(brow + ks * 32);
        acc = __builtin_amdgcn_mfma_f32_16x16x32_f16(a, bf, acc, 0, 0, 0);
    }

    // lane holds rows m0+quad*4+{0..3} = (den,num) for d0 and d0+1, col t0+l15
    const int d0 = (m0 + quad * 4) >> 1;   // even
    const int t  = t0 + l15;
    const float q0 = qoutT[((b * DIM) + d0) * SEQ + t];       // coalesced
    const float q1 = qoutT[((b * DIM) + d0 + 1) * SEQ + t];
    float2 o;
    o.x = q0 * acc[1] / acc[0];
    o.y = q1 * acc[3] / acc[2];
    *(float2*)(out + ((b * SEQ) + t) * DIM + d0) = o;
}

// ---------------------------------------------------------------------------
extern "C" void kernel_launch(void* const* d_in, const int* in_sizes, int n_in,
                              void* d_out, int out_size, void* d_ws, size_t ws_size,
                              hipStream_t stream) {
    const float* x   = (const float*)d_in[0];
    const float* Wq  = (const float*)d_in[1];
    const float* bq  = (const float*)d_in[2];
    const float* Wk  = (const float*)d_in[3];
    const float* bk  = (const float*)d_in[4];
    const float* Wv  = (const float*)d_in[5];
    const float* bv  = (const float*)d_in[6];
    const float* pos = (const float*)d_in[7];

    float* outp = (float*)d_out;
    char*  ws   = (char*)d_ws;

    _Float16* ep_h  = (_Float16*)(ws);                      // 512 KB
    _Float16* ekk   = (_Float16*)(ws + (512 << 10));        // 1 MB
    float*    qoutT = (float*)   (ws + (1536 << 10));       // 1 MB

    k_proj<<<256, 256, 0, stream>>>(x, Wq, bq, Wk, bk, Wv, bv, pos, qoutT, ekk, ep_h);
    k_aft <<<256, 512, 0, stream>>>(ekk, ep_h, qoutT, outp);
}